// Round 1
// baseline (107.082 us; speedup 1.0000x reference)
//
#include <hip/hip_runtime.h>

// Render_78907139162146: z-buffered triangle rasterizer, 256 tris -> 256x256 RGBA,
// bilinear sample from 3x1024x1024 uvmap.
//
// Sequential-scan semantics reduce per-pixel to: winner = last triangle (index
// order) with inside && z >= running max, zbuf init = global min vertex z.
// Bit-exactness vs numpy reference requires: no FMA contraction, exact op
// order, and float64-internal linspace (np.linspace computes f64 then casts).

#define S 256
#define TMAX 256

__global__ __launch_bounds__(256) void render_kernel(
    const float* __restrict__ tris,
    const float* __restrict__ uvs,
    const float* __restrict__ uvmap,
    float* __restrict__ out,
    int T)
{
#pragma clang fp contract(off)
    // Per-triangle record (AoS, stride 24 floats = 96 B, 16B-aligned groups):
    //  0:Bx 1:By 2:(Ay-By) 3:(Ax-Bx)   -> pAB = (px-Bx)*f2 - (py-By)*f3
    //  4:Cx 5:Cy 6:(By-Cy) 7:(Bx-Cx)   -> pCB = (px-Cx)*f6 - (py-Cy)*f7
    //  8:Ax 9:Ay 10:(Cy-Ay) 11:(Cx-Ax) -> pCA = (px-Ax)*f10 - (py-Ay)*f11
    // 12:ws 13:Az 14:Bz 15:Cz 16:valid 17..22: uv*2-1 (u0x,u0y,u1x,u1y,u2x,u2y)
    __shared__ float sd[TMAX][24];
    __shared__ float zred[256];

    const int tid = threadIdx.x;

    // ---- stage triangle records + per-thread zmin ----
    float zl = 3.0e38f;
    for (int t = tid; t < T; t += 256) {
        const float* p = tris + t * 9;
        float Ax = p[0], Ay = p[1], Az = p[2];
        float Bx = p[3], By = p[4], Bz = p[5];
        float Cx = p[6], Cy = p[7], Cz = p[8];
        float w = (Bx - Ax) * (Cy - Ay) - (By - Ay) * (Cx - Ax);
        bool valid = (w >= 1e-9f);
        sd[t][0] = Bx;  sd[t][1] = By;  sd[t][2]  = Ay - By; sd[t][3]  = Ax - Bx;
        sd[t][4] = Cx;  sd[t][5] = Cy;  sd[t][6]  = By - Cy; sd[t][7]  = Bx - Cx;
        sd[t][8] = Ax;  sd[t][9] = Ay;  sd[t][10] = Cy - Ay; sd[t][11] = Cx - Ax;
        sd[t][12] = valid ? w : 1.0f;
        sd[t][13] = Az; sd[t][14] = Bz; sd[t][15] = Cz;
        sd[t][16] = valid ? 1.0f : 0.0f;
        const float* q = uvs + t * 6;
        sd[t][17] = q[0] * 2.0f - 1.0f;
        sd[t][18] = q[1] * 2.0f - 1.0f;
        sd[t][19] = q[2] * 2.0f - 1.0f;
        sd[t][20] = q[3] * 2.0f - 1.0f;
        sd[t][21] = q[4] * 2.0f - 1.0f;
        sd[t][22] = q[5] * 2.0f - 1.0f;
        zl = fminf(zl, fminf(Az, fminf(Bz, Cz)));
    }
    zred[tid] = zl;
    __syncthreads();
    for (int s = 128; s > 0; s >>= 1) {
        if (tid < s) zred[tid] = fminf(zred[tid], zred[tid + s]);
        __syncthreads();
    }
    const float zmin = zred[0];

    // ---- per-pixel rasterization loop ----
    const int i = blockIdx.x;  // output row
    const int j = tid;         // output col
    // pts[i,j] = (lin[j], lin[255-i]); np.linspace computes in f64, casts f32.
    const float px = (float)(-1.0 + (double)j * (2.0 / 255.0));
    const float py = (float)(-1.0 + (double)(S - 1 - i) * (2.0 / 255.0));

    float zcur = zmin;
    int win = -1;
    float w1w = 0.0f, w2w = 0.0f;

    for (int t = 0; t < T; ++t) {
        float pAB = (px - sd[t][0]) * sd[t][2]  - (py - sd[t][1]) * sd[t][3];
        float pCB = (px - sd[t][4]) * sd[t][6]  - (py - sd[t][5]) * sd[t][7];
        float pCA = (px - sd[t][8]) * sd[t][10] - (py - sd[t][9]) * sd[t][11];
        float prod = fmaxf(pAB, 0.0f) * fmaxf(pCB, 0.0f) * fmaxf(pCA, 0.0f);
        bool inside = (prod > 0.0f) && (sd[t][16] != 0.0f);
        if (inside) {
            float ws = sd[t][12];
            float w1 = pCB / ws;
            float w2 = pCA / ws;
            float w3 = (1.0f - w1) - w2;
            float z = (w1 * sd[t][13] + w2 * sd[t][14]) + w3 * sd[t][15];
            if (z >= zcur) { zcur = z; win = t; w1w = w1; w2w = w2; }
        }
    }

    // ---- epilogue: bilinear texture sample for the winning triangle ----
    float r = 0.0f, g = 0.0f, b = 0.0f, a = 0.0f;
    if (win >= 0) {
        a = 1.0f;
        float w1 = w1w, w2 = w2w;
        float w3 = (1.0f - w1) - w2;
        float ux = (w1 * sd[win][17] + w2 * sd[win][19]) + w3 * sd[win][21];
        float uy = (w1 * sd[win][18] + w2 * sd[win][20]) + w3 * sd[win][22];
        float X = ((ux + 1.0f) * 0.5f) * 1023.0f;
        float Y = ((uy + 1.0f) * 0.5f) * 1023.0f;
        float x0 = floorf(X), y0 = floorf(Y);
        float wx = X - x0, wy = Y - y0;
        float w00 = (1.0f - wx) * (1.0f - wy);
        float w10 = wx * (1.0f - wy);
        float w01 = (1.0f - wx) * wy;
        float w11 = wx * wy;
        float xs1 = x0 + 1.0f, ys1 = y0 + 1.0f;
        bool xin0 = (x0  >= 0.0f) && (x0  <= 1023.0f);
        bool xin1 = (xs1 >= 0.0f) && (xs1 <= 1023.0f);
        bool yin0 = (y0  >= 0.0f) && (y0  <= 1023.0f);
        bool yin1 = (ys1 >= 0.0f) && (ys1 <= 1023.0f);
        int xi0 = (int)fminf(fmaxf(x0,  0.0f), 1023.0f);
        int xi1 = (int)fminf(fmaxf(xs1, 0.0f), 1023.0f);
        int yi0 = (int)fminf(fmaxf(y0,  0.0f), 1023.0f);
        int yi1 = (int)fminf(fmaxf(ys1, 0.0f), 1023.0f);
        float acc[3];
        #pragma unroll
        for (int c = 0; c < 3; ++c) {
            const float* img = uvmap + c * (1024 * 1024);
            float v00 = (xin0 && yin0) ? img[yi0 * 1024 + xi0] : 0.0f;
            float v10 = (xin1 && yin0) ? img[yi0 * 1024 + xi1] : 0.0f;
            float v01 = (xin0 && yin1) ? img[yi1 * 1024 + xi0] : 0.0f;
            float v11 = (xin1 && yin1) ? img[yi1 * 1024 + xi1] : 0.0f;
            acc[c] = ((v00 * w00 + v10 * w10) + v01 * w01) + v11 * w11;
        }
        r = acc[0]; g = acc[1]; b = acc[2];
    }

    const int base = i * S + j;
    out[0 * S * S + base] = r;
    out[1 * S * S + base] = g;
    out[2 * S * S + base] = b;
    out[3 * S * S + base] = a;
}

extern "C" void kernel_launch(void* const* d_in, const int* in_sizes, int n_in,
                              void* d_out, int out_size, void* d_ws, size_t ws_size,
                              hipStream_t stream) {
    const float* tris  = (const float*)d_in[0];
    const float* uvs   = (const float*)d_in[1];
    const float* uvmap = (const float*)d_in[2];
    float* out = (float*)d_out;
    int T = in_sizes[0] / 9;
    if (T > TMAX) T = TMAX;
    render_kernel<<<dim3(S), dim3(256), 0, stream>>>(tris, uvs, uvmap, out, T);
}

// Round 2
// 89.017 us; speedup vs baseline: 1.2029x; 1.2029x over previous
//
#include <hip/hip_runtime.h>

// Render_78907139162146: z-buffered triangle rasterizer, 256 tris -> 256x256 RGBA,
// bilinear sample from 3x1024x1024 uvmap.
//
// Scan semantics reduce per-pixel to: winner = last triangle (index order) with
// inside && z >= running max, zbuf init = global min vertex z == "last argmax of
// z subject to z >= zmin". That merge is associative over index-ordered chunks
// (later chunk wins ties via >=), so we split the triangle loop across 4 wave
// groups per block (block=1024) for 4 waves/SIMD latency hiding.
//
// Bit-exactness vs numpy reference: no FMA contraction, exact op order,
// float64-internal linspace (np.linspace computes f64 then casts f32).

#define S 256
#define TMAX 256
#define NC 4      // triangle chunks per block
#define BT 1024   // threads per block (16 waves)

__global__ __launch_bounds__(BT) void render_kernel(
    const float* __restrict__ tris,
    const float* __restrict__ uvs,
    const float* __restrict__ uvmap,
    float* __restrict__ out,
    int T)
{
#pragma clang fp contract(off)
    // Per-triangle record, 6 x float4 (96 B, 16B-aligned):
    //  r0: Bx, By, (Ay-By), (Ax-Bx)    -> pAB = (px-Bx)*r0.z - (py-By)*r0.w
    //  r1: Cx, Cy, (By-Cy), (Bx-Cx)    -> pCB = (px-Cx)*r1.z - (py-Cy)*r1.w
    //  r2: Ax, Ay, (Cy-Ay), (Cx-Ax)    -> pCA = (px-Ax)*r2.z - (py-Ay)*r2.w
    //  r3: ws, Az, Bz, Cz
    //  r4: valid, u0x, u0y, u1x
    //  r5: u1y, u2x, u2y, pad
    __shared__ float4 sd[TMAX][6];
    __shared__ float  zred[BT];
    __shared__ float4 cand[NC][S];   // z, w1, w2, win

    const int tid = threadIdx.x;

    // ---- stage triangle records + per-thread zmin ----
    float zl = 3.0e38f;
    for (int t = tid; t < T; t += BT) {
        const float* p = tris + t * 9;
        float Ax = p[0], Ay = p[1], Az = p[2];
        float Bx = p[3], By = p[4], Bz = p[5];
        float Cx = p[6], Cy = p[7], Cz = p[8];
        float w = (Bx - Ax) * (Cy - Ay) - (By - Ay) * (Cx - Ax);
        bool valid = (w >= 1e-9f);
        const float* q = uvs + t * 6;
        sd[t][0] = make_float4(Bx, By, Ay - By, Ax - Bx);
        sd[t][1] = make_float4(Cx, Cy, By - Cy, Bx - Cx);
        sd[t][2] = make_float4(Ax, Ay, Cy - Ay, Cx - Ax);
        sd[t][3] = make_float4(valid ? w : 1.0f, Az, Bz, Cz);
        sd[t][4] = make_float4(valid ? 1.0f : 0.0f,
                               q[0] * 2.0f - 1.0f, q[1] * 2.0f - 1.0f, q[2] * 2.0f - 1.0f);
        sd[t][5] = make_float4(q[3] * 2.0f - 1.0f, q[4] * 2.0f - 1.0f, q[5] * 2.0f - 1.0f, 0.0f);
        zl = fminf(zl, fminf(Az, fminf(Bz, Cz)));
    }
    zred[tid] = zl;
    __syncthreads();
    for (int s = BT / 2; s > 0; s >>= 1) {
        if (tid < s) zred[tid] = fminf(zred[tid], zred[tid + s]);
        __syncthreads();
    }
    const float zmin = zred[0];

    // ---- per-pixel rasterization over this wave-group's triangle chunk ----
    const int i = blockIdx.x;      // output row
    const int c = tid >> 8;        // triangle chunk 0..3
    const int j = tid & (S - 1);   // output col
    // pts[i,j] = (lin[j], lin[255-i]); np.linspace computes in f64, casts f32.
    const float px = (float)(-1.0 + (double)j * (2.0 / 255.0));
    const float py = (float)(-1.0 + (double)(S - 1 - i) * (2.0 / 255.0));

    const int cs   = (T + NC - 1) / NC;
    const int tbeg = c * cs;
    const int tend = (tbeg + cs < T) ? (tbeg + cs) : T;

    float zcur = zmin;
    int win = -1;
    float w1w = 0.0f, w2w = 0.0f;

    for (int t = tbeg; t < tend; ++t) {
        float4 r0 = sd[t][0];
        float4 r1 = sd[t][1];
        float4 r2 = sd[t][2];
        float4 r3 = sd[t][3];
        float vld = sd[t][4].x;
        float pAB = (px - r0.x) * r0.z - (py - r0.y) * r0.w;
        float pCB = (px - r1.x) * r1.z - (py - r1.y) * r1.w;
        float pCA = (px - r2.x) * r2.z - (py - r2.y) * r2.w;
        float prod = fmaxf(pAB, 0.0f) * fmaxf(pCB, 0.0f) * fmaxf(pCA, 0.0f);
        bool inside = (prod > 0.0f) && (vld != 0.0f);
        if (inside) {
            float w1 = pCB / r3.x;
            float w2 = pCA / r3.x;
            float w3 = (1.0f - w1) - w2;
            float z = (w1 * r3.y + w2 * r3.z) + w3 * r3.w;
            if (z >= zcur) { zcur = z; win = t; w1w = w1; w2w = w2; }
        }
    }
    cand[c][j] = make_float4(zcur, w1w, w2w, (float)win);
    __syncthreads();

    // ---- merge chunk candidates (chunk order = triangle order, >= = later wins) ----
    if (tid < S) {
        float zb = 0.0f, w1 = 0.0f, w2 = 0.0f;
        int w = -1;
        #pragma unroll
        for (int k = 0; k < NC; ++k) {
            float4 ck = cand[k][tid];
            int cw = (int)ck.w;
            if (cw >= 0 && (w < 0 || ck.x >= zb)) {
                zb = ck.x; w1 = ck.y; w2 = ck.z; w = cw;
            }
        }

        // ---- epilogue: bilinear texture sample for the winning triangle ----
        float r = 0.0f, g = 0.0f, b = 0.0f, a = 0.0f;
        if (w >= 0) {
            a = 1.0f;
            float w3 = (1.0f - w1) - w2;
            float4 r4 = sd[w][4];
            float4 r5 = sd[w][5];
            float ux = (w1 * r4.y + w2 * r4.w) + w3 * r5.y;
            float uy = (w1 * r4.z + w2 * r5.x) + w3 * r5.z;
            float X = ((ux + 1.0f) * 0.5f) * 1023.0f;
            float Y = ((uy + 1.0f) * 0.5f) * 1023.0f;
            float x0 = floorf(X), y0 = floorf(Y);
            float wx = X - x0, wy = Y - y0;
            float w00 = (1.0f - wx) * (1.0f - wy);
            float w10 = wx * (1.0f - wy);
            float w01 = (1.0f - wx) * wy;
            float w11 = wx * wy;
            float xs1 = x0 + 1.0f, ys1 = y0 + 1.0f;
            bool xin0 = (x0  >= 0.0f) && (x0  <= 1023.0f);
            bool xin1 = (xs1 >= 0.0f) && (xs1 <= 1023.0f);
            bool yin0 = (y0  >= 0.0f) && (y0  <= 1023.0f);
            bool yin1 = (ys1 >= 0.0f) && (ys1 <= 1023.0f);
            int xi0 = (int)fminf(fmaxf(x0,  0.0f), 1023.0f);
            int xi1 = (int)fminf(fmaxf(xs1, 0.0f), 1023.0f);
            int yi0 = (int)fminf(fmaxf(y0,  0.0f), 1023.0f);
            int yi1 = (int)fminf(fmaxf(ys1, 0.0f), 1023.0f);
            float acc[3];
            #pragma unroll
            for (int ch = 0; ch < 3; ++ch) {
                const float* img = uvmap + ch * (1024 * 1024);
                float v00 = (xin0 && yin0) ? img[yi0 * 1024 + xi0] : 0.0f;
                float v10 = (xin1 && yin0) ? img[yi0 * 1024 + xi1] : 0.0f;
                float v01 = (xin0 && yin1) ? img[yi1 * 1024 + xi0] : 0.0f;
                float v11 = (xin1 && yin1) ? img[yi1 * 1024 + xi1] : 0.0f;
                acc[ch] = ((v00 * w00 + v10 * w10) + v01 * w01) + v11 * w11;
            }
            r = acc[0]; g = acc[1]; b = acc[2];
        }

        const int base = i * S + tid;
        out[0 * S * S + base] = r;
        out[1 * S * S + base] = g;
        out[2 * S * S + base] = b;
        out[3 * S * S + base] = a;
    }
}

extern "C" void kernel_launch(void* const* d_in, const int* in_sizes, int n_in,
                              void* d_out, int out_size, void* d_ws, size_t ws_size,
                              hipStream_t stream) {
    const float* tris  = (const float*)d_in[0];
    const float* uvs   = (const float*)d_in[1];
    const float* uvmap = (const float*)d_in[2];
    float* out = (float*)d_out;
    int T = in_sizes[0] / 9;
    if (T > TMAX) T = TMAX;
    render_kernel<<<dim3(S), dim3(BT), 0, stream>>>(tris, uvs, uvmap, out, T);
}